// Round 10
// baseline (176.044 us; speedup 1.0000x reference)
//
#include <hip/hip_runtime.h>
#include <hip/hip_bf16.h>

typedef __attribute__((ext_vector_type(8))) short short8;
typedef __attribute__((ext_vector_type(4))) float f32x4;
typedef __attribute__((ext_vector_type(16))) float f32x16;
typedef unsigned short u16;
typedef unsigned int u32;

__device__ __forceinline__ void gload_lds16(const void* g, void* l) {
  typedef const __attribute__((address_space(1))) u32 gu32;
  typedef __attribute__((address_space(3))) u32 lu32;
  __builtin_amdgcn_global_load_lds((gu32*)g, (lu32*)l, 16, 0, 0);
}

__device__ __forceinline__ u16 f2bf(float f) {
  union { float f; u32 u; } v; v.f = f;
  u32 u = v.u + 0x7FFFu + ((v.u >> 16) & 1u);
  return (u16)(u >> 16);
}

__device__ __forceinline__ u32 cvtpk(float lo, float hiv) {
  u32 r;
  asm("v_cvt_pk_bf16_f32 %0, %1, %2" : "=v"(r) : "v"(lo), "v"(hiv));
  return r;
}

__device__ __forceinline__ void plswap(u32& a, u32& b) {
  asm("v_permlane32_swap_b32 %0, %1" : "+v"(a), "+v"(b));
}

__device__ __forceinline__ float fexp2(float x) {
  float r;
  asm("v_exp_f32 %0, %1" : "=v"(r) : "v"(x));
  return r;
}

__device__ __forceinline__ short8 lds_read8(const u16* base, int byteoff) {
  return *(const short8*)((const char*)base + byteoff);
}

// ---------------- fp32 -> bf16 cast of the 4 weights only ----------------
__global__ __launch_bounds__(256) void cast_w_kernel(
    const float* __restrict__ wv, const float* __restrict__ wu,
    const float* __restrict__ wov, const float* __restrict__ wou,
    u16* __restrict__ dst) {
  const long N0 = 262144, N1 = N0 + 786432, N2 = N1 + 262144, N3 = N2 + 262144;
  long i = (long)(blockIdx.x * 256 + threadIdx.x) * 8;
  if (i >= N3) return;
  const float* s;
  if (i < N0) s = wv + i;
  else if (i < N1) s = wu + (i - N0);
  else if (i < N2) s = wov + (i - N1);
  else s = wou + (i - N2);
  float4 a = *(const float4*)s;
  float4 b = *(const float4*)(s + 4);
  short8 o;
  o[0] = (short)f2bf(a.x); o[1] = (short)f2bf(a.y);
  o[2] = (short)f2bf(a.z); o[3] = (short)f2bf(a.w);
  o[4] = (short)f2bf(b.x); o[5] = (short)f2bf(b.y);
  o[6] = (short)f2bf(b.z); o[7] = (short)f2bf(b.w);
  *(short8*)(dst + i) = o;
}

// ---------------- C[M,N] = A[M,K] * B[N,K]^T, bf16 in, OutT out ----------------
template<int BM, int BN, int MR, int NR, typename OutT>
__global__ __launch_bounds__(256) void gemm_bt(
    OutT* __restrict__ C, const u16* __restrict__ A, const u16* __restrict__ B,
    int N, int K) {
  __shared__ u16 As[BM * 64];
  __shared__ u16 Bs[BN * 64];
  const int tid = threadIdx.x;
  const int l = tid & 63, w = tid >> 6;
  const int wr = w >> 1, wc = w & 1;
  const int bm = blockIdx.x * BM, bn = blockIdx.y * BN;
  const int srow = l >> 3, sslot = (l & 7) ^ srow;

  f32x4 acc[MR][NR] = {};

  const u16* Ag = A + (long)(bm + srow) * K + sslot * 8;
  const u16* Bg = B + (long)(bn + srow) * K + sslot * 8;
  constexpr int CA = BM / 32, CB = BN / 32;

  for (int kt = 0; kt < K; kt += 64) {
#pragma unroll
    for (int c = 0; c < CA; ++c) {
      int ch = w * CA + c;
      gload_lds16(Ag + (long)ch * 8 * K + kt, (char*)As + ch * 1024);
    }
#pragma unroll
    for (int c = 0; c < CB; ++c) {
      int ch = w * CB + c;
      gload_lds16(Bg + (long)ch * 8 * K + kt, (char*)Bs + ch * 1024);
    }
    __syncthreads();
    short8 af[MR][2], bf[NR][2];
#pragma unroll
    for (int i = 0; i < MR; ++i)
#pragma unroll
      for (int kk = 0; kk < 2; ++kk) {
        int row = wr * (MR * 16) + i * 16 + (l & 15);
        af[i][kk] = lds_read8(As, row * 128 + (((kk * 4 + (l >> 4)) ^ (l & 7)) * 16));
      }
#pragma unroll
    for (int j = 0; j < NR; ++j)
#pragma unroll
      for (int kk = 0; kk < 2; ++kk) {
        int col = wc * (NR * 16) + j * 16 + (l & 15);
        bf[j][kk] = lds_read8(Bs, col * 128 + (((kk * 4 + (l >> 4)) ^ (l & 7)) * 16));
      }
#pragma unroll
    for (int kk = 0; kk < 2; ++kk)
#pragma unroll
      for (int i = 0; i < MR; ++i)
#pragma unroll
        for (int j = 0; j < NR; ++j)
          acc[i][j] = __builtin_amdgcn_mfma_f32_16x16x32_bf16(
              af[i][kk], bf[j][kk], acc[i][j], 0, 0, 0);
    __syncthreads();
  }
#pragma unroll
  for (int i = 0; i < MR; ++i)
#pragma unroll
    for (int j = 0; j < NR; ++j) {
      int row = bm + wr * (MR * 16) + i * 16 + (l >> 4) * 4;
      int col = bn + wc * (NR * 16) + j * 16 + (l & 15);
#pragma unroll
      for (int r = 0; r < 4; ++r) {
        if constexpr (sizeof(OutT) == 4) {
          C[(long)(row + r) * N + col] = acc[i][j][r];
        } else {
          ((u16*)C)[(long)(row + r) * N + col] = f2bf(acc[i][j][r]);
        }
      }
    }
}

// ---------------- gemm with fp32 A (cast fused into staging): C = A32 * B^T ----
// BM=128, BN=64, MR=4, NR=2: 16 MFMA per 2-barrier iter per wave.
__global__ __launch_bounds__(256) void gemm_a32(
    u16* __restrict__ C, const float* __restrict__ A, const u16* __restrict__ B,
    int N, int K) {
  constexpr int BM = 128, BN = 64, MR = 4, NR = 2;
  __shared__ u16 As[BM * 64];
  __shared__ u16 Bs[BN * 64];
  const int tid = threadIdx.x;
  const int l = tid & 63, w = tid >> 6;
  const int wr = w >> 1, wc = w & 1;
  const int bm = blockIdx.x * BM, bn = blockIdx.y * BN;
  const int srow = l >> 3, sslot = (l & 7) ^ srow;

  f32x4 acc[MR][NR] = {};
  const u16* Bg = B + (long)(bn + srow) * K + sslot * 8;

  for (int kt = 0; kt < K; kt += 64) {
#pragma unroll
    for (int c = 0; c < 2; ++c) {
      int ch = w * 2 + c;
      gload_lds16(Bg + (long)ch * 8 * K + kt, (char*)Bs + ch * 1024);
    }
#pragma unroll
    for (int it = 0; it < 4; ++it) {
      int c = tid + it * 256;           // 1024 chunks: row 0..127 x slot 0..7
      int row = c >> 3, slot = c & 7;
      const float* src = A + (long)(bm + row) * K + kt + slot * 8;
      float4 a = *(const float4*)src;
      float4 b = *(const float4*)(src + 4);
      union { u32 u[4]; short8 s; } pk;
      pk.u[0] = cvtpk(a.x, a.y);
      pk.u[1] = cvtpk(a.z, a.w);
      pk.u[2] = cvtpk(b.x, b.y);
      pk.u[3] = cvtpk(b.z, b.w);
      *(short8*)((char*)As + row * 128 + ((slot ^ (row & 7)) * 16)) = pk.s;
    }
    __syncthreads();
    short8 af[MR][2], bf[NR][2];
#pragma unroll
    for (int i = 0; i < MR; ++i)
#pragma unroll
      for (int kk = 0; kk < 2; ++kk) {
        int row = wr * (MR * 16) + i * 16 + (l & 15);
        af[i][kk] = lds_read8(As, row * 128 + (((kk * 4 + (l >> 4)) ^ (l & 7)) * 16));
      }
#pragma unroll
    for (int j = 0; j < NR; ++j)
#pragma unroll
      for (int kk = 0; kk < 2; ++kk) {
        int col = wc * (NR * 16) + j * 16 + (l & 15);
        bf[j][kk] = lds_read8(Bs, col * 128 + (((kk * 4 + (l >> 4)) ^ (l & 7)) * 16));
      }
#pragma unroll
    for (int kk = 0; kk < 2; ++kk)
#pragma unroll
      for (int i = 0; i < MR; ++i)
#pragma unroll
        for (int j = 0; j < NR; ++j)
          acc[i][j] = __builtin_amdgcn_mfma_f32_16x16x32_bf16(
              af[i][kk], bf[j][kk], acc[i][j], 0, 0, 0);
    __syncthreads();
  }
#pragma unroll
  for (int i = 0; i < MR; ++i)
#pragma unroll
    for (int j = 0; j < NR; ++j) {
      int row = bm + wr * (MR * 16) + i * 16 + (l >> 4) * 4;
      int col = bn + wc * (NR * 16) + j * 16 + (l & 15);
#pragma unroll
      for (int r = 0; r < 4; ++r)
        C[(long)(row + r) * N + col] = f2bf(acc[i][j][r]);
    }
}

// ---------------- V transpose: Vt[b][h][d][t] from qkv v-part ----------------
__global__ __launch_bounds__(256) void vtrans_kernel(
    u16* __restrict__ Vt, const u16* __restrict__ QKV) {
  constexpr int T = 2048, LDQ = 3072;
  __shared__ u16 L[64 * 80];
  const int tid = threadIdx.x;
  const int t0 = blockIdx.x * 64, bh = blockIdx.y;
  const int b = bh >> 4, h = bh & 15;
  const u16* src = QKV + (long)b * T * LDQ + 2048 + h * 64;
#pragma unroll
  for (int it = 0; it < 2; ++it) {
    int row = (tid >> 3) + it * 32;
    int d0 = (tid & 7) * 8;
    short8 v = *(const short8*)(src + (long)(t0 + row) * LDQ + d0);
#pragma unroll
    for (int j = 0; j < 8; ++j)
      L[(d0 + j) * 80 + row] = (u16)(short)v[j];
  }
  __syncthreads();
  u16* dst = Vt + (long)bh * 64 * T + t0;
#pragma unroll
  for (int it = 0; it < 2; ++it) {
    int d = (tid >> 3) + it * 32;
    int c = (tid & 7) * 8;
    *(short8*)(dst + (long)d * T + c) = *(const short8*)(&L[d * 80 + c]);
  }
}

// ---------------- flash attention: swapped 32x32, max-free softmax,
// triple-buffered LDS + counted vmcnt (loads stay in flight across barriers).
// grid (bh=64 fast, qt=8 slow): same-bh blocks land on one XCD -> K/V L2-hit.
// 8 waves x 32 q-rows; 2 blocks/CU.  (Body identical to the verified R8 kernel.)
__global__ __launch_bounds__(512, 4) void attn_kernel(
    u16* __restrict__ Y, const u16* __restrict__ QKV, const u16* __restrict__ Vt) {
  constexpr int T = 2048, LDQ = 3072, NT = T / 64;
  constexpr float SC = 0.18033688011112042f;   // (1/8) * log2(e)
  __shared__ u16 SMEM[24576];                  // 3 x (Ks 8KB | Vs 8KB) = 48 KB
  const int tid = threadIdx.x, l = tid & 63, w = tid >> 6;
  const int lq = l & 31, hi = l >> 5;
  const int bh = blockIdx.x, qt = blockIdx.y;
  const int b = bh >> 4, h = bh & 15;
  const long base = (long)b * T * LDQ;
  const int q0 = qt * 256 + w * 32;

  // Q as B-operand, raw bf16 (scale applied post-MFMA in fp32). Loaded first:
  // these are the OLDEST vmem ops, so counted vmcnt waits below cover them.
  short8 qf[4];
#pragma unroll
  for (int ks = 0; ks < 4; ++ks)
    qf[ks] = *(const short8*)(QKV + base + (long)(q0 + lq) * LDQ + h * 64 +
                              ks * 16 + hi * 8);

  const short8 ONES = {(short)0x3F80, (short)0x3F80, (short)0x3F80, (short)0x3F80,
                       (short)0x3F80, (short)0x3F80, (short)0x3F80, (short)0x3F80};

  f32x16 o0 = {}, o1 = {}, olr = {};   // O^T d[0,32), d[32,64), denominator

  // staging: 512 K-chunks + 512 V-chunks; 1 of each per thread (2 loads/STAGE)
  const int c = tid;
  const int kr = c >> 3, ds = (c & 7) ^ (kr & 7);
  const u16* Kg = QKV + base + 1024 + h * 64;
  const u16* Vg = Vt + (long)bh * 64 * T;

  auto STAGE = [&](int kt, int s) {
    u16* Kd = SMEM + s * 8192;
    u16* Vd = Kd + 4096;
    gload_lds16(Kg + (long)(kt + kr) * LDQ + ds * 8, (char*)Kd + c * 16);
    gload_lds16(Vg + (long)kr * T + kt + ds * 8, (char*)Vd + c * 16);
  };

  const int pslA[4] = {((0 + hi) ^ (lq & 7)) * 16, ((2 + hi) ^ (lq & 7)) * 16,
                       ((4 + hi) ^ (lq & 7)) * 16, ((6 + hi) ^ (lq & 7)) * 16};

  auto COMPUTE = [&](const u16* Ks, const u16* Vs) {
    f32x16 p0 = {}, p1 = {};
    __builtin_amdgcn_s_setprio(1);
#pragma unroll
    for (int ks = 0; ks < 4; ++ks) {
      short8 ka = lds_read8(Ks, lq * 128 + pslA[ks]);
      short8 kb = lds_read8(Ks, (32 + lq) * 128 + pslA[ks]);
      p0 = __builtin_amdgcn_mfma_f32_32x32x16_bf16(ka, qf[ks], p0, 0, 0, 0);
      p1 = __builtin_amdgcn_mfma_f32_32x32x16_bf16(kb, qf[ks], p1, 0, 0, 0);
    }
    __builtin_amdgcn_s_setprio(0);
    // p = 2^(s*SC): scale in fp32, no max-subtraction (scores tiny)
    p0 = p0 * SC;
    p1 = p1 * SC;
#pragma unroll
    for (int r = 0; r < 16; ++r) p0[r] = fexp2(p0[r]);
#pragma unroll
    for (int r = 0; r < 16; ++r) p1[r] = fexp2(p1[r]);
    __builtin_amdgcn_s_setprio(1);
#pragma unroll
    for (int ks = 0; ks < 4; ++ks) {
      const f32x16& ps = (ks < 2) ? p0 : p1;
      const int r0 = (ks & 1) * 8;
      u32 uA = cvtpk(ps[r0 + 0], ps[r0 + 1]);
      u32 uB = cvtpk(ps[r0 + 2], ps[r0 + 3]);
      u32 uC = cvtpk(ps[r0 + 4], ps[r0 + 5]);
      u32 uD = cvtpk(ps[r0 + 6], ps[r0 + 7]);
      plswap(uA, uC);
      plswap(uB, uD);
      union { u32 u[4]; short8 s; } pb;
      pb.u[0] = uA; pb.u[1] = uB; pb.u[2] = uC; pb.u[3] = uD;
      short8 va = lds_read8(Vs, lq * 128 + pslA[ks]);
      short8 vb = lds_read8(Vs, (32 + lq) * 128 + pslA[ks]);
      o0 = __builtin_amdgcn_mfma_f32_32x32x16_bf16(va, pb.s, o0, 0, 0, 0);
      o1 = __builtin_amdgcn_mfma_f32_32x32x16_bf16(vb, pb.s, o1, 0, 0, 0);
      olr = __builtin_amdgcn_mfma_f32_32x32x16_bf16(ONES, pb.s, olr, 0, 0, 0);
    }
    __builtin_amdgcn_s_setprio(0);
  };

  // prologue: 2 tiles in flight
  STAGE(0, 0);
  STAGE(64, 1);
  for (int t = 0; t < NT; ++t) {
    // counted wait: tile t's loads landed; tile t+1's stay in flight.
    if (t + 1 < NT) {
      asm volatile("s_waitcnt vmcnt(2)" ::: "memory");
    } else {
      asm volatile("s_waitcnt vmcnt(0)" ::: "memory");
    }
    __builtin_amdgcn_s_barrier();
    __builtin_amdgcn_sched_barrier(0);
    // prefetch tile t+2 into the buffer COMPUTE(t-1) released at this barrier
    if (t + 2 < NT) STAGE((t + 2) * 64, (t + 2) % 3);
    const u16* Ks = SMEM + (t % 3) * 8192;
    COMPUTE(Ks, Ks + 4096);
  }

  // epilogue: O^T -> LDS (swizzled, 256 rows x 128B = 32KB) -> coalesced store
  __syncthreads();
  float inv = 1.0f / olr[0];
  const int row = w * 32 + lq;
#pragma unroll
  for (int df = 0; df < 2; ++df)
#pragma unroll
    for (int r = 0; r < 16; ++r) {
      int d = df * 32 + (r & 3) + 8 * (r >> 2) + 4 * hi;
      float v = (df ? o1[r] : o0[r]) * inv;
      *(u16*)((char*)SMEM + row * 128 + (((d >> 3) ^ (row & 7)) * 16) + (d & 7) * 2) =
          f2bf(v);
    }
  __syncthreads();
#pragma unroll
  for (int it = 0; it < 4; ++it) {
    int cc = tid + it * 512;         // 2048 chunks: q 0..255 x 8 d-slots
    int q = cc >> 3, g = cc & 7;
    int pg = g ^ (q & 7);
    short8 vv = *(const short8*)((const char*)SMEM + q * 128 + pg * 16);
    *(short8*)(Y + (long)(b * T + qt * 256 + q) * 1024 + h * 64 + g * 8) = vv;
  }
}

__global__ void ws_too_small_kernel(float* out) { out[0] = 3.0e38f; }

// ---------------- launch ----------------
extern "C" void kernel_launch(void* const* d_in, const int* in_sizes, int n_in,
                              void* d_out, int out_size, void* d_ws, size_t ws_size,
                              hipStream_t stream) {
  (void)in_sizes; (void)n_in; (void)out_size;
  const float* x   = (const float*)d_in[0];
  const float* wv  = (const float*)d_in[1];
  const float* wu  = (const float*)d_in[2];
  const float* wov = (const float*)d_in[3];
  const float* wou = (const float*)d_in[4];
  float* out = (float*)d_out;
  u16* ws = (u16*)d_ws;

  u16* wvb  = ws;                // W_qkv_v  [256,1024]
  u16* wub  = ws + 262144;       // W_qkv_u  [3072,256]
  u16* wovb = ws + 1048576;      // W_o_v    [256,1024]
  u16* woub = ws + 1310720;      // W_o_u    [1024,256]
  u16* t    = ws + 1572864;      // x@Wv^T   [8192,256]
  u16* qkv  = ws + 3670016;      // [8192,3072]
  u16* vt   = ws + 28835840;     // Vt [B,H,64,2048]
  u16* yb   = ws + 37224448;     // attn out [8192,1024]
  u16* z    = ws + 45613056;     // y@Wov^T  [8192,256]

  if (ws_size < 95420416ull) {
    ws_too_small_kernel<<<1, 1, 0, stream>>>(out);
    return;
  }

  cast_w_kernel<<<dim3(768), dim3(256), 0, stream>>>(wv, wu, wov, wou, ws);
  // t = x @ Wv^T          M=8192 N=256  K=1024 (fp32 A, cast fused; 128x64 tile)
  gemm_a32<<<dim3(64, 4), dim3(256), 0, stream>>>(t, x, wvb, 256, 1024);
  // qkv = t @ Wu^T        M=8192 N=3072 K=256
  gemm_bt<128, 128, 4, 4, u16><<<dim3(64, 24), dim3(256), 0, stream>>>(qkv, t, wub, 3072, 256);
  // Vt = transpose of V part
  vtrans_kernel<<<dim3(32, 64), dim3(256), 0, stream>>>(vt, qkv);
  // attention: grid (bh fast, qt slow) for XCD-local K/V
  attn_kernel<<<dim3(64, 8), dim3(512), 0, stream>>>(yb, qkv, vt);
  // z = y @ Wov^T         M=8192 N=256  K=1024 (128x64 tile)
  gemm_bt<128, 64, 4, 2, u16><<<dim3(64, 4), dim3(256), 0, stream>>>(z, yb, wovb, 256, 1024);
  // out = z @ Wou^T       M=8192 N=1024 K=256  (fp32 out)
  gemm_bt<128, 128, 4, 4, float><<<dim3(64, 8), dim3(256), 0, stream>>>(out, z, woub, 1024, 256);
}

// Round 11
// 167.824 us; speedup vs baseline: 1.0490x; 1.0490x over previous
//
#include <hip/hip_runtime.h>
#include <hip/hip_bf16.h>

typedef __attribute__((ext_vector_type(8))) short short8;
typedef __attribute__((ext_vector_type(4))) float f32x4;
typedef __attribute__((ext_vector_type(16))) float f32x16;
typedef unsigned short u16;
typedef unsigned int u32;

__device__ __forceinline__ void gload_lds16(const void* g, void* l) {
  typedef const __attribute__((address_space(1))) u32 gu32;
  typedef __attribute__((address_space(3))) u32 lu32;
  __builtin_amdgcn_global_load_lds((gu32*)g, (lu32*)l, 16, 0, 0);
}

__device__ __forceinline__ u16 f2bf(float f) {
  union { float f; u32 u; } v; v.f = f;
  u32 u = v.u + 0x7FFFu + ((v.u >> 16) & 1u);
  return (u16)(u >> 16);
}

__device__ __forceinline__ u32 cvtpk(float lo, float hiv) {
  u32 r;
  asm("v_cvt_pk_bf16_f32 %0, %1, %2" : "=v"(r) : "v"(lo), "v"(hiv));
  return r;
}

__device__ __forceinline__ void plswap(u32& a, u32& b) {
  asm("v_permlane32_swap_b32 %0, %1" : "+v"(a), "+v"(b));
}

__device__ __forceinline__ float fexp2(float x) {
  float r;
  asm("v_exp_f32 %0, %1" : "=v"(r) : "v"(x));
  return r;
}

__device__ __forceinline__ short8 lds_read8(const u16* base, int byteoff) {
  return *(const short8*)((const char*)base + byteoff);
}

// ---------------- fp32 -> bf16 cast of the 4 weights only ----------------
__global__ __launch_bounds__(256) void cast_w_kernel(
    const float* __restrict__ wv, const float* __restrict__ wu,
    const float* __restrict__ wov, const float* __restrict__ wou,
    u16* __restrict__ dst) {
  const long N0 = 262144, N1 = N0 + 786432, N2 = N1 + 262144, N3 = N2 + 262144;
  long i = (long)(blockIdx.x * 256 + threadIdx.x) * 8;
  if (i >= N3) return;
  const float* s;
  if (i < N0) s = wv + i;
  else if (i < N1) s = wu + (i - N0);
  else if (i < N2) s = wov + (i - N1);
  else s = wou + (i - N2);
  float4 a = *(const float4*)s;
  float4 b = *(const float4*)(s + 4);
  short8 o;
  o[0] = (short)f2bf(a.x); o[1] = (short)f2bf(a.y);
  o[2] = (short)f2bf(a.z); o[3] = (short)f2bf(a.w);
  o[4] = (short)f2bf(b.x); o[5] = (short)f2bf(b.y);
  o[6] = (short)f2bf(b.z); o[7] = (short)f2bf(b.w);
  *(short8*)(dst + i) = o;
}

// ---------------- C[M,N] = A[M,K] * B[N,K]^T, bf16 in, OutT out ----------------
template<int BM, int BN, int MR, int NR, typename OutT>
__global__ __launch_bounds__(256) void gemm_bt(
    OutT* __restrict__ C, const u16* __restrict__ A, const u16* __restrict__ B,
    int N, int K) {
  __shared__ u16 As[BM * 64];
  __shared__ u16 Bs[BN * 64];
  const int tid = threadIdx.x;
  const int l = tid & 63, w = tid >> 6;
  const int wr = w >> 1, wc = w & 1;
  const int bm = blockIdx.x * BM, bn = blockIdx.y * BN;
  const int srow = l >> 3, sslot = (l & 7) ^ srow;

  f32x4 acc[MR][NR] = {};

  const u16* Ag = A + (long)(bm + srow) * K + sslot * 8;
  const u16* Bg = B + (long)(bn + srow) * K + sslot * 8;
  constexpr int CA = BM / 32, CB = BN / 32;

  for (int kt = 0; kt < K; kt += 64) {
#pragma unroll
    for (int c = 0; c < CA; ++c) {
      int ch = w * CA + c;
      gload_lds16(Ag + (long)ch * 8 * K + kt, (char*)As + ch * 1024);
    }
#pragma unroll
    for (int c = 0; c < CB; ++c) {
      int ch = w * CB + c;
      gload_lds16(Bg + (long)ch * 8 * K + kt, (char*)Bs + ch * 1024);
    }
    __syncthreads();
    short8 af[MR][2], bf[NR][2];
#pragma unroll
    for (int i = 0; i < MR; ++i)
#pragma unroll
      for (int kk = 0; kk < 2; ++kk) {
        int row = wr * (MR * 16) + i * 16 + (l & 15);
        af[i][kk] = lds_read8(As, row * 128 + (((kk * 4 + (l >> 4)) ^ (l & 7)) * 16));
      }
#pragma unroll
    for (int j = 0; j < NR; ++j)
#pragma unroll
      for (int kk = 0; kk < 2; ++kk) {
        int col = wc * (NR * 16) + j * 16 + (l & 15);
        bf[j][kk] = lds_read8(Bs, col * 128 + (((kk * 4 + (l >> 4)) ^ (l & 7)) * 16));
      }
#pragma unroll
    for (int kk = 0; kk < 2; ++kk)
#pragma unroll
      for (int i = 0; i < MR; ++i)
#pragma unroll
        for (int j = 0; j < NR; ++j)
          acc[i][j] = __builtin_amdgcn_mfma_f32_16x16x32_bf16(
              af[i][kk], bf[j][kk], acc[i][j], 0, 0, 0);
    __syncthreads();
  }
#pragma unroll
  for (int i = 0; i < MR; ++i)
#pragma unroll
    for (int j = 0; j < NR; ++j) {
      int row = bm + wr * (MR * 16) + i * 16 + (l >> 4) * 4;
      int col = bn + wc * (NR * 16) + j * 16 + (l & 15);
#pragma unroll
      for (int r = 0; r < 4; ++r) {
        if constexpr (sizeof(OutT) == 4) {
          C[(long)(row + r) * N + col] = acc[i][j][r];
        } else {
          ((u16*)C)[(long)(row + r) * N + col] = f2bf(acc[i][j][r]);
        }
      }
    }
}

// ---------------- gemm with fp32 A (cast fused into staging): C = A32 * B^T ----
__global__ __launch_bounds__(256) void gemm_a32(
    u16* __restrict__ C, const float* __restrict__ A, const u16* __restrict__ B,
    int N, int K) {
  constexpr int BM = 64, BN = 64, MR = 2, NR = 2;
  __shared__ u16 As[BM * 64];
  __shared__ u16 Bs[BN * 64];
  const int tid = threadIdx.x;
  const int l = tid & 63, w = tid >> 6;
  const int wr = w >> 1, wc = w & 1;
  const int bm = blockIdx.x * BM, bn = blockIdx.y * BN;
  const int srow = l >> 3, sslot = (l & 7) ^ srow;

  f32x4 acc[MR][NR] = {};
  const u16* Bg = B + (long)(bn + srow) * K + sslot * 8;

  for (int kt = 0; kt < K; kt += 64) {
#pragma unroll
    for (int c = 0; c < 2; ++c) {
      int ch = w * 2 + c;
      gload_lds16(Bg + (long)ch * 8 * K + kt, (char*)Bs + ch * 1024);
    }
#pragma unroll
    for (int it = 0; it < 2; ++it) {
      int c = tid + it * 256;           // 512 chunks: row 0..63 x slot 0..7
      int row = c >> 3, slot = c & 7;
      const float* src = A + (long)(bm + row) * K + kt + slot * 8;
      float4 a = *(const float4*)src;
      float4 b = *(const float4*)(src + 4);
      union { u32 u[4]; short8 s; } pk;
      pk.u[0] = cvtpk(a.x, a.y);
      pk.u[1] = cvtpk(a.z, a.w);
      pk.u[2] = cvtpk(b.x, b.y);
      pk.u[3] = cvtpk(b.z, b.w);
      *(short8*)((char*)As + row * 128 + ((slot ^ (row & 7)) * 16)) = pk.s;
    }
    __syncthreads();
    short8 af[MR][2], bf[NR][2];
#pragma unroll
    for (int i = 0; i < MR; ++i)
#pragma unroll
      for (int kk = 0; kk < 2; ++kk) {
        int row = wr * (MR * 16) + i * 16 + (l & 15);
        af[i][kk] = lds_read8(As, row * 128 + (((kk * 4 + (l >> 4)) ^ (l & 7)) * 16));
      }
#pragma unroll
    for (int j = 0; j < NR; ++j)
#pragma unroll
      for (int kk = 0; kk < 2; ++kk) {
        int col = wc * (NR * 16) + j * 16 + (l & 15);
        bf[j][kk] = lds_read8(Bs, col * 128 + (((kk * 4 + (l >> 4)) ^ (l & 7)) * 16));
      }
#pragma unroll
    for (int kk = 0; kk < 2; ++kk)
#pragma unroll
      for (int i = 0; i < MR; ++i)
#pragma unroll
        for (int j = 0; j < NR; ++j)
          acc[i][j] = __builtin_amdgcn_mfma_f32_16x16x32_bf16(
              af[i][kk], bf[j][kk], acc[i][j], 0, 0, 0);
    __syncthreads();
  }
#pragma unroll
  for (int i = 0; i < MR; ++i)
#pragma unroll
    for (int j = 0; j < NR; ++j) {
      int row = bm + wr * (MR * 16) + i * 16 + (l >> 4) * 4;
      int col = bn + wc * (NR * 16) + j * 16 + (l & 15);
#pragma unroll
      for (int r = 0; r < 4; ++r)
        C[(long)(row + r) * N + col] = f2bf(acc[i][j][r]);
    }
}

// ---------------- V transpose: Vt[b][h][d][t] from qkv v-part ----------------
__global__ __launch_bounds__(256) void vtrans_kernel(
    u16* __restrict__ Vt, const u16* __restrict__ QKV) {
  constexpr int T = 2048, LDQ = 3072;
  __shared__ u16 L[64 * 80];
  const int tid = threadIdx.x;
  const int t0 = blockIdx.x * 64, bh = blockIdx.y;
  const int b = bh >> 4, h = bh & 15;
  const u16* src = QKV + (long)b * T * LDQ + 2048 + h * 64;
#pragma unroll
  for (int it = 0; it < 2; ++it) {
    int row = (tid >> 3) + it * 32;
    int d0 = (tid & 7) * 8;
    short8 v = *(const short8*)(src + (long)(t0 + row) * LDQ + d0);
#pragma unroll
    for (int j = 0; j < 8; ++j)
      L[(d0 + j) * 80 + row] = (u16)(short)v[j];
  }
  __syncthreads();
  u16* dst = Vt + (long)bh * 64 * T + t0;
#pragma unroll
  for (int it = 0; it < 2; ++it) {
    int d = (tid >> 3) + it * 32;
    int c = (tid & 7) * 8;
    *(short8*)(dst + (long)d * T + c) = *(const short8*)(&L[d * 80 + c]);
  }
}

// ---------------- flash attention: swapped 32x32, max-free softmax,
// WITHIN-WAVE SOFTWARE PIPELINE: QK(t+1) MFMAs run under exp(t)'s latency.
// 3-buffer LDS; per iter: [STAGE(t+2) | exp(t) | vmcnt+barrier | QK(t+1) | PV(t) | barrier].
// grid (bh=64 fast, qt=8 slow) -> K/V XCD-local (proven: FETCH 144->30 MB).
__global__ __launch_bounds__(512, 2) void attn_kernel(
    u16* __restrict__ Y, const u16* __restrict__ QKV, const u16* __restrict__ Vt) {
  constexpr int T = 2048, LDQ = 3072, NT = T / 64;
  constexpr float SC = 0.18033688011112042f;   // (1/8) * log2(e)
  __shared__ u16 SMEM[24576];                  // 3 x (Ks 8KB | Vs 8KB) = 48 KB
  const int tid = threadIdx.x, l = tid & 63, w = tid >> 6;
  const int lq = l & 31, hi = l >> 5;
  const int bh = blockIdx.x, qt = blockIdx.y;
  const int b = bh >> 4, h = bh & 15;
  const long base = (long)b * T * LDQ;
  const int q0 = qt * 256 + w * 32;

  // Q as B-operand (oldest vmem ops -> covered by the prologue counted wait)
  short8 qf[4];
#pragma unroll
  for (int ks = 0; ks < 4; ++ks)
    qf[ks] = *(const short8*)(QKV + base + (long)(q0 + lq) * LDQ + h * 64 +
                              ks * 16 + hi * 8);

  const short8 ONES = {(short)0x3F80, (short)0x3F80, (short)0x3F80, (short)0x3F80,
                       (short)0x3F80, (short)0x3F80, (short)0x3F80, (short)0x3F80};

  f32x16 o0 = {}, o1 = {}, olr = {};

  const int c = tid;
  const int kr = c >> 3, ds = (c & 7) ^ (kr & 7);
  const u16* Kg = QKV + base + 1024 + h * 64;
  const u16* Vg = Vt + (long)bh * 64 * T;

  auto STAGE = [&](int kt, int s) {
    u16* Kd = SMEM + s * 8192;
    u16* Vd = Kd + 4096;
    gload_lds16(Kg + (long)(kt + kr) * LDQ + ds * 8, (char*)Kd + c * 16);
    gload_lds16(Vg + (long)kr * T + kt + ds * 8, (char*)Vd + c * 16);
  };

  const int pslA[4] = {((0 + hi) ^ (lq & 7)) * 16, ((2 + hi) ^ (lq & 7)) * 16,
                       ((4 + hi) ^ (lq & 7)) * 16, ((6 + hi) ^ (lq & 7)) * 16};

  auto QK = [&](const u16* Ks, f32x16& s0, f32x16& s1) {
    __builtin_amdgcn_s_setprio(1);
#pragma unroll
    for (int ks = 0; ks < 4; ++ks) {
      short8 ka = lds_read8(Ks, lq * 128 + pslA[ks]);
      short8 kb = lds_read8(Ks, (32 + lq) * 128 + pslA[ks]);
      s0 = __builtin_amdgcn_mfma_f32_32x32x16_bf16(ka, qf[ks], s0, 0, 0, 0);
      s1 = __builtin_amdgcn_mfma_f32_32x32x16_bf16(kb, qf[ks], s1, 0, 0, 0);
    }
    __builtin_amdgcn_s_setprio(0);
  };

  auto PV = [&](const f32x16& p0, const f32x16& p1, const u16* Vs) {
    __builtin_amdgcn_s_setprio(1);
#pragma unroll
    for (int ks = 0; ks < 4; ++ks) {
      const f32x16& ps = (ks < 2) ? p0 : p1;
      const int r0 = (ks & 1) * 8;
      u32 uA = cvtpk(ps[r0 + 0], ps[r0 + 1]);
      u32 uB = cvtpk(ps[r0 + 2], ps[r0 + 3]);
      u32 uC = cvtpk(ps[r0 + 4], ps[r0 + 5]);
      u32 uD = cvtpk(ps[r0 + 6], ps[r0 + 7]);
      plswap(uA, uC);
      plswap(uB, uD);
      union { u32 u[4]; short8 s; } pb;
      pb.u[0] = uA; pb.u[1] = uB; pb.u[2] = uC; pb.u[3] = uD;
      short8 va = lds_read8(Vs, lq * 128 + pslA[ks]);
      short8 vb = lds_read8(Vs, (32 + lq) * 128 + pslA[ks]);
      o0 = __builtin_amdgcn_mfma_f32_32x32x16_bf16(va, pb.s, o0, 0, 0, 0);
      o1 = __builtin_amdgcn_mfma_f32_32x32x16_bf16(vb, pb.s, o1, 0, 0, 0);
      olr = __builtin_amdgcn_mfma_f32_32x32x16_bf16(ONES, pb.s, olr, 0, 0, 0);
    }
    __builtin_amdgcn_s_setprio(0);
  };

  // prologue: 2 tiles in flight; wait covers Q loads (4) + STAGE(0) (2)
  STAGE(0, 0);
  STAGE(64, 1);
  asm volatile("s_waitcnt vmcnt(2)" ::: "memory");
  __builtin_amdgcn_s_barrier();
  __builtin_amdgcn_sched_barrier(0);
  f32x16 s0 = {}, s1 = {};
  QK(SMEM, s0, s1);

  for (int t = 0; t < NT; ++t) {
    if (t + 2 < NT) STAGE((t + 2) * 64, (t + 2) % 3);
    // exp(t): issue early; latency hides under QK(t+1)
    f32x16 p0 = s0 * SC, p1 = s1 * SC;
#pragma unroll
    for (int r = 0; r < 16; ++r) p0[r] = fexp2(p0[r]);
#pragma unroll
    for (int r = 0; r < 16; ++r) p1[r] = fexp2(p1[r]);
    f32x16 n0 = {}, n1 = {};
    if (t + 1 < NT) {
      // own STAGE(t+1) landed...
      if (t + 2 < NT) {
        asm volatile("s_waitcnt vmcnt(2)" ::: "memory");
      } else {
        asm volatile("s_waitcnt vmcnt(0)" ::: "memory");
      }
      // ...and all other waves' STAGE(t+1) writes made visible
      __builtin_amdgcn_s_barrier();
      __builtin_amdgcn_sched_barrier(0);
      QK(SMEM + ((t + 1) % 3) * 8192, n0, n1);
    }
    PV(p0, p1, SMEM + (t % 3) * 8192 + 4096);
    __builtin_amdgcn_s_barrier();   // release V(t)'s buffer for STAGE(t+3)
    s0 = n0;
    s1 = n1;
  }

  // epilogue: O^T -> LDS (swizzled) -> coalesced row-major store
  __syncthreads();
  float inv = 1.0f / olr[0];
  const int row = w * 32 + lq;
#pragma unroll
  for (int df = 0; df < 2; ++df)
#pragma unroll
    for (int r = 0; r < 16; ++r) {
      int d = df * 32 + (r & 3) + 8 * (r >> 2) + 4 * hi;
      float v = (df ? o1[r] : o0[r]) * inv;
      *(u16*)((char*)SMEM + row * 128 + (((d >> 3) ^ (row & 7)) * 16) + (d & 7) * 2) =
          f2bf(v);
    }
  __syncthreads();
#pragma unroll
  for (int it = 0; it < 4; ++it) {
    int cc = tid + it * 512;         // 2048 chunks: q 0..255 x 8 d-slots
    int q = cc >> 3, g = cc & 7;
    int pg = g ^ (q & 7);
    short8 vv = *(const short8*)((const char*)SMEM + q * 128 + pg * 16);
    *(short8*)(Y + (long)(b * T + qt * 256 + q) * 1024 + h * 64 + g * 8) = vv;
  }
}

__global__ void ws_too_small_kernel(float* out) { out[0] = 3.0e38f; }

// ---------------- launch ----------------
extern "C" void kernel_launch(void* const* d_in, const int* in_sizes, int n_in,
                              void* d_out, int out_size, void* d_ws, size_t ws_size,
                              hipStream_t stream) {
  (void)in_sizes; (void)n_in; (void)out_size;
  const float* x   = (const float*)d_in[0];
  const float* wv  = (const float*)d_in[1];
  const float* wu  = (const float*)d_in[2];
  const float* wov = (const float*)d_in[3];
  const float* wou = (const float*)d_in[4];
  float* out = (float*)d_out;
  u16* ws = (u16*)d_ws;

  u16* wvb  = ws;                // W_qkv_v  [256,1024]
  u16* wub  = ws + 262144;       // W_qkv_u  [3072,256]
  u16* wovb = ws + 1048576;      // W_o_v    [256,1024]
  u16* woub = ws + 1310720;      // W_o_u    [1024,256]
  u16* t    = ws + 1572864;      // x@Wv^T   [8192,256]
  u16* qkv  = ws + 3670016;      // [8192,3072]
  u16* vt   = ws + 28835840;     // Vt [B,H,64,2048]
  u16* yb   = ws + 37224448;     // attn out [8192,1024]
  u16* z    = ws + 45613056;     // y@Wov^T  [8192,256]

  if (ws_size < 95420416ull) {
    ws_too_small_kernel<<<1, 1, 0, stream>>>(out);
    return;
  }

  cast_w_kernel<<<dim3(768), dim3(256), 0, stream>>>(wv, wu, wov, wou, ws);
  // t = x @ Wv^T          M=8192 N=256  K=1024 (fp32 A, cast fused; 64^2 tile)
  gemm_a32<<<dim3(128, 4), dim3(256), 0, stream>>>(t, x, wvb, 256, 1024);
  // qkv = t @ Wu^T        M=8192 N=3072 K=256
  gemm_bt<128, 128, 4, 4, u16><<<dim3(64, 24), dim3(256), 0, stream>>>(qkv, t, wub, 3072, 256);
  // Vt = transpose of V part
  vtrans_kernel<<<dim3(32, 64), dim3(256), 0, stream>>>(vt, qkv);
  // attention: grid (bh fast, qt slow) for XCD-local K/V
  attn_kernel<<<dim3(64, 8), dim3(512), 0, stream>>>(yb, qkv, vt);
  // z = y @ Wov^T         M=8192 N=256  K=1024 (64^2 tile)
  gemm_bt<64, 64, 2, 2, u16><<<dim3(128, 4), dim3(256), 0, stream>>>(z, yb, wovb, 256, 1024);
  // out = z @ Wou^T       M=8192 N=1024 K=256  (fp32 out)
  gemm_bt<128, 128, 4, 4, float><<<dim3(64, 8), dim3(256), 0, stream>>>(out, z, woub, 1024, 256);
}